// Round 1
// baseline (33.530 us; speedup 1.0000x reference)
//
#include <hip/hip_runtime.h>

#define FMAP 160
#define NANCH (FMAP * FMAP)      // 25600
#define NCLS 8
#define MAXGT 50
#define BATCH 32
#define NT 256
#define APT 4                    // anchors per thread
#define ANCH_PER_BLOCK (NT * APT)            // 1024
#define BLOCKS_PER_B (NANCH / ANCH_PER_BLOCK) // 25

__device__ __forceinline__ float sl1(float x) {
    float ax = fabsf(x);
    return ax < 1.f ? 0.5f * x * x : ax - 0.5f;
}

__global__ __launch_bounds__(NT) void detloss_main(
    const float* __restrict__ cls, const float* __restrict__ reg,
    const float* __restrict__ anchors, const float* __restrict__ gtb,
    const int* __restrict__ gtl, const int* __restrict__ nb,
    float* __restrict__ partials)
{
    const int b  = blockIdx.y;
    const int n0 = blockIdx.x * ANCH_PER_BLOCK;
    const int t  = threadIdx.x;

    __shared__ float4 gbox[MAXGT];
    __shared__ float  garea[MAXGT];
    __shared__ int    glab[MAXGT];
    if (t < MAXGT) {
        float4 g = ((const float4*)gtb)[b * MAXGT + t];
        gbox[t]  = g;
        garea[t] = (g.z - g.x) * (g.w - g.y);
        glab[t]  = gtl[b * MAXGT + t];
    }
    const int num = nb[b];
    __syncthreads();

    float x0[APT], y0[APT], x1[APT], y1[APT], a1[APT];
    float bi[APT], bu[APT];
    int   bidx[APT];
    float r0[APT], r1[APT], r2[APT], r3[APT];
    float acx[APT], acy[APT], aw[APT], ah[APT];

#pragma unroll
    for (int k = 0; k < APT; k++) {
        int n = n0 + t + k * NT;
        float4 a = ((const float4*)anchors)[n];
        float aww = a.z - a.x, ahh = a.w - a.y;
        float cx0 = a.x + 0.5f * aww, cy0 = a.y + 0.5f * ahh;
        const float* rp = reg + (size_t)b * 4 * NANCH + n;
        float rr0 = rp[0], rr1 = rp[NANCH], rr2 = rp[2 * NANCH], rr3 = rp[3 * NANCH];
        float tx = rr0 * 2.f - 1.f, ty = rr1 * 2.f - 1.f;
        float cx = cx0 + tx * aww / 4.f, cy = cy0 + ty * ahh / 4.f;
        float w = aww * __expf(rr2), h = ahh * __expf(rr3);
        x0[k] = cx - 0.5f * w; y0[k] = cy - 0.5f * h;
        x1[k] = cx + 0.5f * w; y1[k] = cy + 0.5f * h;
        a1[k] = (x1[k] - x0[k]) * (y1[k] - y0[k]);
        bi[k] = -1.f; bu[k] = 1.f; bidx[k] = 0;
        r0[k] = rr0; r1[k] = rr1; r2[k] = rr2; r3[k] = rr3;
        acx[k] = cx0; acy[k] = cy0; aw[k] = aww; ah[k] = ahh;
    }

    // IoU max/argmax loop over valid GTs (uniform count per block)
    for (int m = 0; m < num; m++) {
        float4 g  = gbox[m];
        float  ga = garea[m];
#pragma unroll
        for (int k = 0; k < APT; k++) {
            float ltx = fmaxf(x0[k], g.x), lty = fmaxf(y0[k], g.y);
            float rbx = fminf(x1[k], g.z), rby = fminf(y1[k], g.w);
            float wx = fmaxf(rbx - ltx, 0.f), wy = fmaxf(rby - lty, 0.f);
            float inter = wx * wy;
            float u = fmaxf(a1[k] + ga - inter, 1e-8f);
            // iou > best  <=>  inter/u > bi/bu  <=>  inter*bu > bi*u  (u,bu > 0)
            bool better = inter * bu[k] > bi[k] * u;
            if (better) { bi[k] = inter; bu[k] = u; bidx[k] = m; }
        }
    }

    float s_np = 0.f, s_nn = 0.f, s_cp = 0.f, s_cn = 0.f, s_bg = 0.f, s_sl = 0.f;
    const float* cbase = cls + (size_t)b * NCLS * NANCH;
    const bool has = num > 0;

#pragma unroll
    for (int k = 0; k < APT; k++) {
        int n = n0 + t + k * NT;
        float l[NCLS];
#pragma unroll
        for (int c = 0; c < NCLS; c++) l[c] = cbase[c * NANCH + n];
        float mx = l[0];
#pragma unroll
        for (int c = 1; c < NCLS; c++) mx = fmaxf(mx, l[c]);
        float s = 0.f;
#pragma unroll
        for (int c = 0; c < NCLS; c++) s += __expf(l[c] - mx);
        float lse   = mx + __logf(s);
        float ce_bg = lse - l[0];

        float iou = bi[k] / bu[k];          // -1 when num==0
        bool pos = has && (iou >= 0.25f);
        bool neg = has && (iou < 0.1f);

        s_bg += ce_bg;
        if (neg) { s_nn += 1.f; s_cn += ce_bg; }
        if (pos) {
            s_np += 1.f;
            int tg = glab[bidx[k]];
            s_cp += lse - l[tg];
            float4 g = gbox[bidx[k]];
            float gw = g.z - g.x, gh = g.w - g.y;
            float gcx = g.x + 0.5f * gw, gcy = g.y + 0.5f * gh;
            float txt = ((gcx - acx[k]) * (4.f / aw[k]) + 1.f) * 0.5f;
            float tyt = ((gcy - acy[k]) * (4.f / ah[k]) + 1.f) * 0.5f;
            float twt = __logf(fmaxf(gw, 1e-6f) / aw[k]);
            float tht = __logf(fmaxf(gh, 1e-6f) / ah[k]);
            s_sl += sl1(r0[k] - txt) + sl1(r1[k] - tyt)
                  + sl1(r2[k] - twt) + sl1(r3[k] - tht);
        }
    }

    // deterministic block reduction: wave shuffle tree, then LDS across 4 waves
#pragma unroll
    for (int o = 32; o > 0; o >>= 1) {
        s_np += __shfl_down(s_np, o, 64);
        s_nn += __shfl_down(s_nn, o, 64);
        s_cp += __shfl_down(s_cp, o, 64);
        s_cn += __shfl_down(s_cn, o, 64);
        s_bg += __shfl_down(s_bg, o, 64);
        s_sl += __shfl_down(s_sl, o, 64);
    }
    __shared__ float red[NT / 64][6];
    const int wid = t >> 6, lane = t & 63;
    if (lane == 0) {
        red[wid][0] = s_np; red[wid][1] = s_nn; red[wid][2] = s_cp;
        red[wid][3] = s_cn; red[wid][4] = s_bg; red[wid][5] = s_sl;
    }
    __syncthreads();
    if (t == 0) {
        float* p = partials + (size_t)(b * BLOCKS_PER_B + blockIdx.x) * 6;
#pragma unroll
        for (int j = 0; j < 6; j++)
            p[j] = red[0][j] + red[1][j] + red[2][j] + red[3][j];
    }
}

__global__ __launch_bounds__(64) void detloss_final(
    const float* __restrict__ partials, const int* __restrict__ nb,
    float* __restrict__ out)
{
    const int t = threadIdx.x;
    float np = 0.f, nn = 0.f, cp = 0.f, cn = 0.f, bg = 0.f, sl = 0.f;
    float clsb = 0.f, regb = 0.f;
    if (t < BATCH) {
        for (int i = 0; i < BLOCKS_PER_B; i++) {
            const float* p = partials + (size_t)(t * BLOCKS_PER_B + i) * 6;
            np += p[0]; nn += p[1]; cp += p[2]; cn += p[3]; bg += p[4]; sl += p[5];
        }
        bool has = nb[t] > 0;
        if (has) {
            float a = (np > 0.f) ? cp / fmaxf(np, 1.f) : 0.f;
            float c = (nn > 0.f) ? cn / fmaxf(nn, 1.f) : 0.f;
            clsb = a + c;
        } else {
            clsb = bg / (float)NANCH;
        }
        regb = (np > 0.f) ? sl / fmaxf(np * 4.f, 1.f) : 0.f;
    }
    float tps = np;   // zero for t >= BATCH
#pragma unroll
    for (int o = 32; o > 0; o >>= 1) {
        clsb += __shfl_down(clsb, o, 64);
        regb += __shfl_down(regb, o, 64);
        tps  += __shfl_down(tps,  o, 64);
    }
    if (t == 0) {
        float clsf = clsb / (float)BATCH;
        float regf = regb / fmaxf(tps, 1.f);
        out[0] = clsf + regf;
        out[1] = clsf;
        out[2] = regf;
        out[3] = tps;
    }
}

extern "C" void kernel_launch(void* const* d_in, const int* in_sizes, int n_in,
                              void* d_out, int out_size, void* d_ws, size_t ws_size,
                              hipStream_t stream) {
    const float* cls     = (const float*)d_in[0];
    const float* reg     = (const float*)d_in[1];
    const float* anchors = (const float*)d_in[2];
    const float* gtb     = (const float*)d_in[3];
    const int*   gtl     = (const int*)d_in[4];
    const int*   nb      = (const int*)d_in[5];
    float* out      = (float*)d_out;
    float* partials = (float*)d_ws;   // BATCH*BLOCKS_PER_B*6 floats = 19.2 KB

    dim3 grid(BLOCKS_PER_B, BATCH);
    detloss_main<<<grid, NT, 0, stream>>>(cls, reg, anchors, gtb, gtl, nb, partials);
    detloss_final<<<1, 64, 0, stream>>>(partials, nb, out);
}

// Round 2
// 31.814 us; speedup vs baseline: 1.0540x; 1.0540x over previous
//
#include <hip/hip_runtime.h>

#define FMAP 160
#define NANCH (FMAP * FMAP)      // 25600
#define NCLS 8
#define MAXGT 50
#define BATCH 32
#define NT 256
#define APT 4                    // anchors per thread
#define ANCH_PER_BLOCK (NT * APT)            // 1024
#define BLOCKS_PER_B (NANCH / ANCH_PER_BLOCK) // 25

__device__ __forceinline__ float sl1(float x) {
    float ax = fabsf(x);
    return ax < 1.f ? 0.5f * x * x : ax - 0.5f;
}

// one IoU max/argmax update against GT box g (area ga, index MIDX)
#define IOU_UPDATE(g, ga, BI, BU, ID, MIDX)                          \
    {                                                                \
        float ltx = fmaxf(x0[k], (g).x), lty = fmaxf(y0[k], (g).y);  \
        float rbx = fminf(x1[k], (g).z), rby = fminf(y1[k], (g).w);  \
        float wx = fmaxf(rbx - ltx, 0.f), wy = fmaxf(rby - lty, 0.f);\
        float inter = wx * wy;                                       \
        float u = fmaxf(a1[k] + (ga) - inter, 1e-8f);                \
        bool better = inter * BU[k] > BI[k] * u;                     \
        BI[k] = better ? inter : BI[k];                              \
        BU[k] = better ? u : BU[k];                                  \
        ID[k] = better ? (MIDX) : ID[k];                             \
    }

__global__ __launch_bounds__(NT) void detloss_main(
    const float* __restrict__ cls, const float* __restrict__ reg,
    const float* __restrict__ anchors, const float* __restrict__ gtb,
    const int* __restrict__ gtl, const int* __restrict__ nb,
    float* __restrict__ partials)
{
    const int b  = blockIdx.y;
    const int n0 = blockIdx.x * ANCH_PER_BLOCK;
    const int t  = threadIdx.x;

    __shared__ float4 gbox[MAXGT];
    __shared__ int    glab[MAXGT];
    if (t < MAXGT) {
        gbox[t] = ((const float4*)gtb)[b * MAXGT + t];
        glab[t] = gtl[b * MAXGT + t];
    }
    const int num = nb[b];
    __syncthreads();

    float x0[APT], y0[APT], x1[APT], y1[APT], a1[APT];
    float r0[APT], r1[APT], r2[APT], r3[APT];
    float acx[APT], acy[APT], aw[APT], ah[APT];
    float l[APT][NCLS];
    const float* cbase = cls + (size_t)b * NCLS * NANCH;

#pragma unroll
    for (int k = 0; k < APT; k++) {
        int n = n0 + t + k * NT;
        float4 a = ((const float4*)anchors)[n];
        float aww = a.z - a.x, ahh = a.w - a.y;
        float cx0 = a.x + 0.5f * aww, cy0 = a.y + 0.5f * ahh;
        const float* rp = reg + (size_t)b * 4 * NANCH + n;
        float rr0 = rp[0], rr1 = rp[NANCH], rr2 = rp[2 * NANCH], rr3 = rp[3 * NANCH];
        // prefetch cls logits now — latency hides under the IoU loop
#pragma unroll
        for (int c = 0; c < NCLS; c++) l[k][c] = cbase[c * NANCH + n];
        float tx = rr0 * 2.f - 1.f, ty = rr1 * 2.f - 1.f;
        float cx = cx0 + tx * aww / 4.f, cy = cy0 + ty * ahh / 4.f;
        float w = aww * __expf(rr2), h = ahh * __expf(rr3);
        x0[k] = cx - 0.5f * w; y0[k] = cy - 0.5f * h;
        x1[k] = cx + 0.5f * w; y1[k] = cy + 0.5f * h;
        a1[k] = (x1[k] - x0[k]) * (y1[k] - y0[k]);
        r0[k] = rr0; r1[k] = rr1; r2[k] = rr2; r3[k] = rr3;
        acx[k] = cx0; acy[k] = cy0; aw[k] = aww; ah[k] = ahh;
    }

    // dual accumulators: even GT indices -> (bie,bue,ide), odd -> (bio,buo,ido)
    float bie[APT], bue[APT], bio[APT], buo[APT];
    int   ide[APT], ido[APT];
#pragma unroll
    for (int k = 0; k < APT; k++) {
        bie[k] = -1.f; bue[k] = 1.f; ide[k] = 0;
        bio[k] = -1.f; buo[k] = 1.f; ido[k] = 0;
    }

    const int npairs = num >> 1;
    float4 gA, gB;
    if (npairs > 0) { gA = gbox[0]; gB = gbox[1]; }
    for (int p = 0; p < npairs; ++p) {
        int mn = 2 * p + 2;                 // prefetch next pair (clamped, branch-free)
        if (mn > MAXGT - 2) mn = MAXGT - 2;
        float4 gA2 = gbox[mn];
        float4 gB2 = gbox[mn + 1];
        float gaA = (gA.z - gA.x) * (gA.w - gA.y);
        float gaB = (gB.z - gB.x) * (gB.w - gB.y);
        int me = 2 * p, mo = me + 1;
#pragma unroll
        for (int k = 0; k < APT; k++) {
            IOU_UPDATE(gA, gaA, bie, bue, ide, me);
            IOU_UPDATE(gB, gaB, bio, buo, ido, mo);
        }
        gA = gA2; gB = gB2;
    }
    if (num & 1) {
        // trailing single GT (even index num-1); gA already holds gbox[num-1]
        float4 g = (npairs > 0) ? gA : gbox[0];
        float ga = (g.z - g.x) * (g.w - g.y);
        int mlast = num - 1;
#pragma unroll
        for (int k = 0; k < APT; k++) IOU_UPDATE(g, ga, bie, bue, ide, mlast);
    }

    // merge even/odd winners; exact first-occurrence tie-break on equal IoU
    float bi[APT], bu[APT];
    int   bidx[APT];
#pragma unroll
    for (int k = 0; k < APT; k++) {
        float ce = bie[k] * buo[k];
        float co = bio[k] * bue[k];
        bool  to = (co > ce) || ((co == ce) && (ido[k] < ide[k]));
        bi[k]   = to ? bio[k] : bie[k];
        bu[k]   = to ? buo[k] : bue[k];
        bidx[k] = to ? ido[k] : ide[k];
    }

    float s_np = 0.f, s_nn = 0.f, s_cp = 0.f, s_cn = 0.f, s_bg = 0.f, s_sl = 0.f;
    const bool has = num > 0;

#pragma unroll
    for (int k = 0; k < APT; k++) {
        float mx = l[k][0];
#pragma unroll
        for (int c = 1; c < NCLS; c++) mx = fmaxf(mx, l[k][c]);
        float s = 0.f;
#pragma unroll
        for (int c = 0; c < NCLS; c++) s += __expf(l[k][c] - mx);
        float lse   = mx + __logf(s);
        float ce_bg = lse - l[k][0];

        float iou = bi[k] / bu[k];          // -1 when num==0
        bool pos = has && (iou >= 0.25f);
        bool neg = has && (iou < 0.1f);

        s_bg += ce_bg;
        if (neg) { s_nn += 1.f; s_cn += ce_bg; }
        if (pos) {
            s_np += 1.f;
            int tg = glab[bidx[k]];
            s_cp += lse - l[k][tg];
            float4 g = gbox[bidx[k]];
            float gw = g.z - g.x, gh = g.w - g.y;
            float gcx = g.x + 0.5f * gw, gcy = g.y + 0.5f * gh;
            float txt = ((gcx - acx[k]) * (4.f / aw[k]) + 1.f) * 0.5f;
            float tyt = ((gcy - acy[k]) * (4.f / ah[k]) + 1.f) * 0.5f;
            float twt = __logf(fmaxf(gw, 1e-6f) / aw[k]);
            float tht = __logf(fmaxf(gh, 1e-6f) / ah[k]);
            s_sl += sl1(r0[k] - txt) + sl1(r1[k] - tyt)
                  + sl1(r2[k] - twt) + sl1(r3[k] - tht);
        }
    }

    // deterministic block reduction: wave shuffle tree, then LDS across 4 waves
#pragma unroll
    for (int o = 32; o > 0; o >>= 1) {
        s_np += __shfl_down(s_np, o, 64);
        s_nn += __shfl_down(s_nn, o, 64);
        s_cp += __shfl_down(s_cp, o, 64);
        s_cn += __shfl_down(s_cn, o, 64);
        s_bg += __shfl_down(s_bg, o, 64);
        s_sl += __shfl_down(s_sl, o, 64);
    }
    __shared__ float red[NT / 64][6];
    const int wid = t >> 6, lane = t & 63;
    if (lane == 0) {
        red[wid][0] = s_np; red[wid][1] = s_nn; red[wid][2] = s_cp;
        red[wid][3] = s_cn; red[wid][4] = s_bg; red[wid][5] = s_sl;
    }
    __syncthreads();
    if (t == 0) {
        float* p = partials + (size_t)(b * BLOCKS_PER_B + blockIdx.x) * 6;
#pragma unroll
        for (int j = 0; j < 6; j++)
            p[j] = red[0][j] + red[1][j] + red[2][j] + red[3][j];
    }
}

__global__ __launch_bounds__(64) void detloss_final(
    const float* __restrict__ partials, const int* __restrict__ nb,
    float* __restrict__ out)
{
    const int t = threadIdx.x;
    float np = 0.f, nn = 0.f, cp = 0.f, cn = 0.f, bg = 0.f, sl = 0.f;
    float clsb = 0.f, regb = 0.f;
    if (t < BATCH) {
        for (int i = 0; i < BLOCKS_PER_B; i++) {
            const float* p = partials + (size_t)(t * BLOCKS_PER_B + i) * 6;
            np += p[0]; nn += p[1]; cp += p[2]; cn += p[3]; bg += p[4]; sl += p[5];
        }
        bool has = nb[t] > 0;
        if (has) {
            float a = (np > 0.f) ? cp / fmaxf(np, 1.f) : 0.f;
            float c = (nn > 0.f) ? cn / fmaxf(nn, 1.f) : 0.f;
            clsb = a + c;
        } else {
            clsb = bg / (float)NANCH;
        }
        regb = (np > 0.f) ? sl / fmaxf(np * 4.f, 1.f) : 0.f;
    }
    float tps = np;   // zero for t >= BATCH
#pragma unroll
    for (int o = 32; o > 0; o >>= 1) {
        clsb += __shfl_down(clsb, o, 64);
        regb += __shfl_down(regb, o, 64);
        tps  += __shfl_down(tps,  o, 64);
    }
    if (t == 0) {
        float clsf = clsb / (float)BATCH;
        float regf = regb / fmaxf(tps, 1.f);
        out[0] = clsf + regf;
        out[1] = clsf;
        out[2] = regf;
        out[3] = tps;
    }
}

extern "C" void kernel_launch(void* const* d_in, const int* in_sizes, int n_in,
                              void* d_out, int out_size, void* d_ws, size_t ws_size,
                              hipStream_t stream) {
    const float* cls     = (const float*)d_in[0];
    const float* reg     = (const float*)d_in[1];
    const float* anchors = (const float*)d_in[2];
    const float* gtb     = (const float*)d_in[3];
    const int*   gtl     = (const int*)d_in[4];
    const int*   nb      = (const int*)d_in[5];
    float* out      = (float*)d_out;
    float* partials = (float*)d_ws;   // BATCH*BLOCKS_PER_B*6 floats = 19.2 KB

    dim3 grid(BLOCKS_PER_B, BATCH);
    detloss_main<<<grid, NT, 0, stream>>>(cls, reg, anchors, gtb, gtl, nb, partials);
    detloss_final<<<1, 64, 0, stream>>>(partials, nb, out);
}